// Round 16
// baseline (215.383 us; speedup 1.0000x reference)
//
#include <hip/hip_runtime.h>
#include <cstdint>
#include <cstddef>

typedef float  f32x4  __attribute__((ext_vector_type(4)));
typedef float  f32x16 __attribute__((ext_vector_type(16)));
typedef short  s16x8  __attribute__((ext_vector_type(8)));

#define DEV __device__ __forceinline__

static constexpr int    DHW       = 32768;       // 8*64*64
static constexpr int    NTOK      = 65536;       // B*D*H*W
static constexpr int    CHUNK_B   = 18432;       // 16384 gh/gl + 1KB e2 + zero slot + pad
static constexpr size_t OUT_ELEMS = 4194304;     // 2*64*32768
static constexpr float  BIGC      = 512.0f;      // positivity bias for uint-compare
static constexpr float  TAU       = 0.015f;      // near-tie refinement threshold
static constexpr int    FLAG_CAP  = 7424;        // sized so ws end == 2,524,416 (proven)

// workspace layout (end = 2,524,416 B)
static constexpr size_t WS_PREP = 0;             // 64*18432 = 1,179,648
static constexpr size_t WS_RESW = 1179648;       // 4*65536*4 (per-quarter winner word)
static constexpr size_t WS_RESB = 2228224;       // 4*65536*1 (chunk | tie-bit)
static constexpr size_t WS_PART = 2490368;       // 1024*4: [0..255] merge d, [256..383] t^2
static constexpr size_t WS_CNT  = 2494464;       // int
static constexpr size_t WS_FLAG = 2494720;       // FLAG_CAP*4 -> end 2,524,416

DEV unsigned f2bf(float f) {            // RNE float -> bf16 bits
  unsigned u = __float_as_uint(f);
  return (u + 0x7FFFu + ((u >> 16) & 1u)) >> 16;
}
DEV float bf2f(unsigned h) { return __uint_as_float(h << 16); }
DEV unsigned med3u(unsigned a, unsigned b, unsigned c) {
  unsigned r;
  asm("v_med3_u32 %0, %1, %2, %3" : "=v"(r) : "v"(a), "v"(b), "v"(c));
  return r;
}
DEV void gl_lds16(const void* g, void* l) {   // 64 lanes x 16B, dest = base + lane*16
  __builtin_amdgcn_global_load_lds(
      (const __attribute__((address_space(1))) unsigned int*)g,
      (__attribute__((address_space(3))) unsigned int*)l, 16, 0, 0);
}

// ---------------- Kernel A: pre-conv + embedding prep --------------------------
// Conv blocks 0..255 (1024 thr): z tile (64ch x 256 tok) staged in LDS ONCE via
// gl_lds16 (cuts z traffic 64->16 MB vs 4x re-read); thread (i=tid&255,
// qtr=tid>>8) computes channels qtr*16..+15 with the proven 4-chain fmaf order.
// Prep blocks 256..271 (1024 thr, 2 units each) build the swizzled codebook.
__global__ __launch_bounds__(1024) void k_pre(const float* __restrict__ z,
    const float* __restrict__ emb, const float* __restrict__ pw, const float* __restrict__ pb,
    float* __restrict__ dout, char* __restrict__ ws)
{
  __shared__ __align__(16) float zlds[64 * 256];   // 64 KB
  const int blk = blockIdx.x, tid = threadIdx.x;
  if (blk == 0 && tid == 0) *(int*)(ws + WS_CNT) = 0;
  if (blk < 256) {
    float* t = dout;
    const int v0 = blk * 256;
    const int b = v0 >> 15, r0 = v0 & (DHW - 1);   // whole block shares b
    const int w = tid >> 6, lane = tid & 63;
#pragma unroll
    for (int k = 0; k < 4; ++k) {                  // wave w stages channels w*4+k
      const int c2 = w * 4 + k;
      gl_lds16(z + (size_t)(b * 64 + c2) * DHW + r0 + lane * 4,
               (char*)zlds + c2 * 1024);
    }
    __syncthreads();
    const int i = tid & 255, qtr = tid >> 8;
    const int v = v0 + i;
    float zr[64];
#pragma unroll
    for (int c2 = 0; c2 < 64; ++c2) zr[c2] = zlds[c2 * 256 + i];  // 2-way free
    const int c0 = qtr * 16;
    for (int c = c0; c < c0 + 16; c += 4) {        // 4 independent chains (ILP)
      const float* w0 = pw + c * 64;
      const float* w1 = pw + (c + 1) * 64;
      const float* w2 = pw + (c + 2) * 64;
      const float* w3 = pw + (c + 3) * 64;
      float a0 = pb[c], a1 = pb[c + 1], a2 = pb[c + 2], a3 = pb[c + 3];
#pragma unroll
      for (int c2 = 0; c2 < 64; ++c2) {            // per-channel order unchanged
        const float zv = zr[c2];
        a0 = fmaf(w0[c2], zv, a0); a1 = fmaf(w1[c2], zv, a1);
        a2 = fmaf(w2[c2], zv, a2); a3 = fmaf(w3[c2], zv, a3);
      }
      t[(size_t)c * NTOK + v]       = a0;
      t[(size_t)(c + 1) * NTOK + v] = a1;
      t[(size_t)(c + 2) * NTOK + v] = a2;
      t[(size_t)(c + 3) * NTOK + v] = a3;
    }
  } else {
    const int tt = (blk - 256) * 1024 + tid;       // 0..16383, 2 units each
#pragma unroll
    for (int uu = 0; uu < 2; ++uu) {
      const int u = tt * 2 + uu;
      const int k = u >> 3, j = u & 7;             // code k, 8-channel group j
      const float* ep = emb + (size_t)k * 64 + j * 8;
      unsigned hw[4], lw[4];
#pragma unroll
      for (int i = 0; i < 4; ++i) {
        float g0 = -2.0f * ep[2 * i], g1 = -2.0f * ep[2 * i + 1];
        unsigned h0 = f2bf(g0); unsigned l0 = f2bf(g0 - bf2f(h0));
        unsigned h1 = f2bf(g1); unsigned l1 = f2bf(g1 - bf2f(h1));
        hw[i] = h0 | (h1 << 16); lw[i] = l0 | (l1 << 16);
      }
      char* base = ws + WS_PREP + (size_t)(k >> 6) * CHUNK_B;
      const int r = k & 63;
      const int swz = (r & 15) << 4;
      char* rowp = base + r * 256;
      *(uint4*)(rowp + ((j * 16) ^ swz))        = make_uint4(hw[0], hw[1], hw[2], hw[3]);
      *(uint4*)(rowp + ((128 + j * 16) ^ swz))  = make_uint4(lw[0], lw[1], lw[2], lw[3]);
      if (j == 0) {
        const float* er = emb + (size_t)k * 64;
        float s = 0.f;
#pragma unroll
        for (int c = 0; c < 64; ++c) s = fmaf(er[c], er[c], s);
        s += BIGC;
        unsigned eh  = f2bf(s);
        float    rs  = s - bf2f(eh);
        unsigned el  = f2bf(rs);
        unsigned el2 = f2bf(rs - bf2f(el));
        *(uint4*)(base + 16384 + r * 16) = make_uint4(eh | (el << 16), el2, 0u, 0u);
        if (r == 0) *(uint4*)(base + 16384 + 1024) = make_uint4(0u, 0u, 0u, 0u);
      }
    }
  }
}

// ---------------- Kernel B: bf16x3 MFMA distance (32x32x16) -------------------
// r15 form verbatim (plateau: 9 structures all 93-98 us). 512 tokens/block
// (16 waves), NQ=4; prologue also accumulates sum(t^2) -> WS_PART[256+gidx].
__global__ __launch_bounds__(1024, 4) void k_dist(float* __restrict__ dout,
                                                  char* __restrict__ ws)
{
  constexpr int NCH = 16;
  __shared__ __align__(16) char smem[2 * CHUNK_B];
  __shared__ float t2s[16];
  const float* t = dout;                       // [64][NTOK]
  const int tid = threadIdx.x;
  const int w = tid >> 6, lane = tid & 63;     // w in [0,16)
  const int l31 = lane & 31, khalf = lane >> 5;
  const int gidx = blockIdx.x >> 2, h = blockIdx.x & 3;
  const int tb = gidx * 512 + w * 32;
  const int tok = tb + l31;

  // ---- B-fragments: t[k][tok], k = kt*16 + khalf*8 + i; also sum t^2 ----
  s16x8 tav[4], tlv[4];
  float t2 = 0.f;
#pragma unroll
  for (int kt = 0; kt < 4; ++kt) {
    const float* tc = t + (size_t)(kt * 16 + khalf * 8) * NTOK + tok;
    float f[8];
#pragma unroll
    for (int i = 0; i < 8; ++i) f[i] = tc[(size_t)i * NTOK];
#pragma unroll
    for (int i = 0; i < 8; ++i) t2 = fmaf(f[i], f[i], t2);
    union { unsigned u[4]; s16x8 v; } xh, xl;
#pragma unroll
    for (int i = 0; i < 4; ++i) {
      unsigned h0 = f2bf(f[2 * i]),     l0 = f2bf(f[2 * i]     - bf2f(h0));
      unsigned h1 = f2bf(f[2 * i + 1]), l1 = f2bf(f[2 * i + 1] - bf2f(h1));
      xh.u[i] = h0 | (h1 << 16); xl.u[i] = l0 | (l1 << 16);
    }
    tav[kt] = xh.v; tlv[kt] = xl.v;
  }
  t2 += __shfl_xor(t2, 32);
#pragma unroll
  for (int m = 1; m <= 16; m <<= 1) t2 += __shfl_xor(t2, m);
  if (lane == 0) t2s[w] = t2;

  s16x8 ones;                                  // B for e2-MFMA: k'=0,1,2 -> 1.0 (khalf 0)
  { union { unsigned u[4]; s16x8 v; } o;
    o.u[0] = khalf ? 0u : 0x3F803F80u;
    o.u[1] = khalf ? 0u : 0x00003F80u;
    o.u[2] = 0u; o.u[3] = 0u; ones = o.v; }

  const char* prep = ws + WS_PREP + (size_t)h * NCH * CHUNK_B;
  const int swz = (l31 & 15) << 4;

  auto stage = [&](int cc) {
    const char* src = prep + (size_t)cc * CHUNK_B;
    char* dst = smem + (size_t)(cc & 1) * CHUNK_B;
    gl_lds16(src + w * 1024 + lane * 16, dst + w * 1024);
    if (w < 2) gl_lds16(src + 16384 + w * 1024 + lane * 16, dst + 16384 + w * 1024);
  };
  stage(0);
  __syncthreads();

  unsigned u1 = 0x7f800000u, u2 = 0x7f800000u;
  int c1 = 0;

  for (int c = 0; c < NCH; ++c) {
    const char* L = smem + (c & 1) * CHUNK_B;
    if (c + 1 < NCH) stage(c + 1);             // issue next-chunk stage early
    f32x16 acc0 = {}, acc1 = {};
    {                                          // e2 seed via MFMA (adds 512+||e||^2)
      const s16x8 e0 = *(const s16x8*)(L + (khalf ? (16384 + 1024) : (16384 + l31 * 16)));
      const s16x8 e1 = *(const s16x8*)(L + (khalf ? (16384 + 1024) : (16384 + (32 + l31) * 16)));
      acc0 = __builtin_amdgcn_mfma_f32_32x32x16_bf16(e0, ones, acc0, 0, 0, 0);
      acc1 = __builtin_amdgcn_mfma_f32_32x32x16_bf16(e1, ones, acc1, 0, 0, 0);
    }
#pragma unroll
    for (int kt = 0; kt < 4; ++kt) {
      const int i0 = (kt * 32 + khalf * 16) ^ swz;
      const s16x8 gh0 = *(const s16x8*)(L + l31 * 256 + i0);
      const s16x8 gl0 = *(const s16x8*)(L + l31 * 256 + (i0 ^ 128));
      const s16x8 gh1 = *(const s16x8*)(L + (32 + l31) * 256 + i0);
      const s16x8 gl1 = *(const s16x8*)(L + (32 + l31) * 256 + (i0 ^ 128));
      acc0 = __builtin_amdgcn_mfma_f32_32x32x16_bf16(gh0, tav[kt], acc0, 0, 0, 0);
      acc0 = __builtin_amdgcn_mfma_f32_32x32x16_bf16(gh0, tlv[kt], acc0, 0, 0, 0);
      acc0 = __builtin_amdgcn_mfma_f32_32x32x16_bf16(gl0, tav[kt], acc0, 0, 0, 0);
      acc1 = __builtin_amdgcn_mfma_f32_32x32x16_bf16(gh1, tav[kt], acc1, 0, 0, 0);
      acc1 = __builtin_amdgcn_mfma_f32_32x32x16_bf16(gh1, tlv[kt], acc1, 0, 0, 0);
      acc1 = __builtin_amdgcn_mfma_f32_32x32x16_bf16(gl1, tav[kt], acc1, 0, 0, 0);
    }
    const unsigned p1 = u1;
#pragma unroll
    for (int q = 0; q < 16; ++q) {
      const unsigned w0 = (unsigned)((q & 3) + 8 * (q >> 2));
      unsigned v0 = (__float_as_uint(acc0[q]) & ~63u) | w0;
      u2 = med3u(u1, v0, u2); u1 = u1 < v0 ? u1 : v0;
      unsigned v1 = (__float_as_uint(acc1[q]) & ~63u) | (w0 + 32u);
      u2 = med3u(u1, v1, u2); u1 = u1 < v1 ? u1 : v1;
    }
    if (u1 != p1) c1 = c;
    __syncthreads();                           // drains vmcnt -> next chunk staged
  }

  u1 |= (unsigned)(khalf * 4);                 // complete wid (bit 2)
  const unsigned o1 = __shfl_xor(u1, 32);
  const unsigned o2 = __shfl_xor(u2, 32);
  const int      oc = __shfl_xor(c1, 32);
  const unsigned am = u1 & ~63u, om = o1 & ~63u;
  const int mycode = c1 * 64 + (int)(u1 & 63u);
  const int ocode  = oc * 64 + (int)(o1 & 63u);
  const bool owins = (om < am) || (om == am && ocode < mycode);
  const unsigned f1 = owins ? o1 : u1;
  const int      fc = owins ? oc : c1;
  const unsigned mx = owins ? am : om;
  unsigned s2 = (u2 & ~63u) < (o2 & ~63u) ? (u2 & ~63u) : (o2 & ~63u);
  s2 = s2 < mx ? s2 : mx;
  if (khalf == 0) {
    const bool nt = (__uint_as_float(s2) - __uint_as_float(f1 & ~63u)) < TAU;
    ((unsigned*)(ws + WS_RESW))[h * 65536 + tok] = f1;
    ((unsigned char*)(ws + WS_RESB))[h * 65536 + tok] =
        (unsigned char)(fc | (nt ? 0x80 : 0));   // fc in 0..15 (4 bits)
  }
  if (h == 0 && tid == 0) {
    float s = 0.f;
#pragma unroll
    for (int i = 0; i < 16; ++i) s += t2s[i];
    ((float*)(ws + WS_PART))[256 + gidx] = s;
  }
}

// ---------------- Kernel PM: fused merge + post-conv ---------------------------
// 256 blocks x 1024 thr. Phase 1 (tid<256): 4-way merge -> code (LDS+fidx),
// flags, metric-loss partial. Phase 2: stage the 256 emb rows ONCE into padded
// LDS (65-float rows, conflict-free). Phase 3: 4-way channel-split conv from LDS.
__global__ __launch_bounds__(1024) void k_postm(const float* __restrict__ emb,
    const float* __restrict__ ow, const float* __restrict__ ob,
    float* __restrict__ dout, char* __restrict__ ws)
{
  __shared__ float qlds[256 * 65];             // 66.56 KB, +1 pad vs 64
  __shared__ int   codes[256];
  __shared__ float ls[4];
  const int tid = threadIdx.x, blk = blockIdx.x;
  if (tid < 256) {
    const int v = blk * 256 + tid;
    const unsigned* resw = (const unsigned*)(ws + WS_RESW);
    const unsigned char* resb = (const unsigned char*)(ws + WS_RESB);
    unsigned k1 = 0xffffffffu, k2 = 0xffffffffu, bw = 0; int bq = 0;
#pragma unroll
    for (int q = 0; q < 4; ++q) {
      const unsigned W = resw[q * 65536 + v];
      const unsigned key = W & ~63u;
      if (key < k1) { k2 = k1; k1 = key; bq = q; bw = W; }
      else          { k2 = key < k2 ? key : k2; }
    }
    const unsigned char bb = resb[bq * 65536 + v];
    const int code = bq * 1024 + (int)(bb & 15u) * 64 + (int)(bw & 63u);
    codes[tid] = code;
    dout[OUT_ELEMS + 2 + v] = (float)code;
    const bool flag = (bb & 0x80u) ||
                      (__uint_as_float(k2) - __uint_as_float(k1) < TAU);
    if (flag) {
      int p = atomicAdd((int*)(ws + WS_CNT), 1);
      if (p < FLAG_CAP) ((int*)(ws + WS_FLAG))[p] = v;
    }
    float acc = __uint_as_float(k1) - 512.0f;  // metric loss (Sterbenz-exact)
#pragma unroll
    for (int m = 1; m <= 32; m <<= 1) acc += __shfl_xor(acc, m);
    if ((tid & 63) == 0) ls[tid >> 6] = acc;
  }
  __syncthreads();
  if (tid == 0)
    ((float*)(ws + WS_PART))[blk] = ls[0] + ls[1] + ls[2] + ls[3];
  // phase 2: stage emb rows (4 threads/token, 16 floats each; coalesced 256B/token)
  {
    const int ti = tid >> 2, p = tid & 3;
    const float* src = emb + (size_t)codes[ti] * 64 + p * 16;
    float* drow = qlds + ti * 65 + p * 16;
#pragma unroll
    for (int j = 0; j < 4; ++j) {
      const float4 qv = *(const float4*)(src + j * 4);
      drow[j * 4]     = qv.x; drow[j * 4 + 1] = qv.y;   // b32 stores (65-pad
      drow[j * 4 + 2] = qv.z; drow[j * 4 + 3] = qv.w;   // breaks 16B align)
    }
  }
  __syncthreads();
  // phase 3: conv (thread i=tid&255, qtr=tid>>8 -> channels qtr*16..+15)
  const int i = tid & 255, qtr = tid >> 8;
  const int v = blk * 256 + i;
  const int b = v >> 15, r = v & (DHW - 1);
  float qr[64];
#pragma unroll
  for (int cch = 0; cch < 64; ++cch) qr[cch] = qlds[i * 65 + cch];  // 2-way free
  float* op = dout + (size_t)b * 64 * DHW + r;
  const int o0 = qtr * 16;
  for (int o = o0; o < o0 + 16; o += 4) {      // 4 independent chains (ILP)
    const float* w0 = ow + o * 64;
    const float* w1 = ow + (o + 1) * 64;
    const float* w2 = ow + (o + 2) * 64;
    const float* w3 = ow + (o + 3) * 64;
    float a0 = ob[o], a1 = ob[o + 1], a2 = ob[o + 2], a3 = ob[o + 3];
#pragma unroll
    for (int cch = 0; cch < 64; ++cch) {       // per-channel order unchanged
      const float qv = qr[cch];
      a0 = fmaf(w0[cch], qv, a0); a1 = fmaf(w1[cch], qv, a1);
      a2 = fmaf(w2[cch], qv, a2); a3 = fmaf(w3[cch], qv, a3);
    }
    op[(size_t)o * DHW]       = a0;
    op[(size_t)(o + 1) * DHW] = a1;
    op[(size_t)(o + 2) * DHW] = a2;
    op[(size_t)(o + 3) * DHW] = a3;
  }
}

// ---------------- Kernel R: f64 re-scan of near-tie tokens + output rewrite ----
// Blocks 0..255 stride flagged slots; corrected tokens also get their 64
// post-conv outputs recomputed (same fmaf order as k_postm -> bit-identical).
// Block 256 finalizes the loss scalars from the 384 partials.
__global__ __launch_bounds__(256) void k_refine(const float* __restrict__ z,
    const float* __restrict__ emb, const float* __restrict__ pw, const float* __restrict__ pb,
    const float* __restrict__ ow, const float* __restrict__ ob,
    float* __restrict__ dout, char* __restrict__ ws)
{
  __shared__ double tdsh[64];
  __shared__ double dred[4]; __shared__ int kred[4];
  __shared__ int kwin;
  const int tid = threadIdx.x;
  if (blockIdx.x == 256) {                     // loss finalizer
    __shared__ float ps[256];
    const float* part = (const float*)(ws + WS_PART);
    const int t4 = tid * 4;
    float s = 0.f;
    if (tid < 96) s = ((part[t4] + part[t4 + 1]) + part[t4 + 2]) + part[t4 + 3];
    ps[tid] = s;
    __syncthreads();
    if (tid == 0) {
      float tot = 0.f;
      for (int i = 0; i < 256; ++i) tot += ps[i];   // fixed order: deterministic
      const float mean = tot / 4194304.0f;
      dout[OUT_ELEMS]     = mean;   // codebook_loss
      dout[OUT_ELEMS + 1] = mean;   // commitment_loss
    }
    return;
  }
  int cv = *(const int*)(ws + WS_CNT);
  if (cv > FLAG_CAP) cv = FLAG_CAP;
  const int lane = tid & 63, wv = tid >> 6;

  for (int slot = blockIdx.x; slot < cv; slot += 256) {
    const int n = ((const int*)(ws + WS_FLAG))[slot];
    const int b = n >> 15, r = n & (DHW - 1);

    if (tid < 64) {                                // recompute token t in f64 (proven chain)
      const float* zp = z + (size_t)b * 64 * DHW + r;
      const float* wr = pw + tid * 64;
      double a = (double)pb[tid];
      for (int c2 = 0; c2 < 64; ++c2)
        a = fma((double)wr[c2], (double)zp[(size_t)c2 * DHW], a);
      tdsh[tid] = a;
    }
    __syncthreads();

    double td[64];                                 // all channels, static-indexed
#pragma unroll
    for (int j = 0; j < 64; ++j) td[j] = tdsh[j];  // broadcast reads

    double dmin = 1e300; int kmin = 0;
    for (int it = 0; it < 16; ++it) {
      const int code = it * 256 + tid;             // ascending per thread
      const float4* e = (const float4*)(emb + (size_t)code * 64);
      double d0 = 0.0, d1 = 0.0;
#pragma unroll
      for (int i = 0; i < 16; ++i) {
        const float4 ev = e[i];
        const double x0 = td[4 * i]     - (double)ev.x; d0 = fma(x0, x0, d0);
        const double x1 = td[4 * i + 1] - (double)ev.y; d1 = fma(x1, x1, d1);
        const double x2 = td[4 * i + 2] - (double)ev.z; d0 = fma(x2, x2, d0);
        const double x3 = td[4 * i + 3] - (double)ev.w; d1 = fma(x3, x3, d1);
      }
      const double d = d0 + d1;
      if (d < dmin) { dmin = d; kmin = code; }     // strict < -> lowest code kept
    }
#pragma unroll
    for (int m = 1; m < 64; m <<= 1) {             // wave argmin, lower-code tiebreak
      const double od = __shfl_xor(dmin, m);
      const int    ok = __shfl_xor(kmin, m);
      if (od < dmin || (od == dmin && ok < kmin)) { dmin = od; kmin = ok; }
    }
    if (lane == 0) { dred[wv] = dmin; kred[wv] = kmin; }
    __syncthreads();
    if (tid == 0) {
#pragma unroll
      for (int i = 1; i < 4; ++i)
        if (dred[i] < dmin || (dred[i] == dmin && kred[i] < kmin)) { dmin = dred[i]; kmin = kred[i]; }
      dout[OUT_ELEMS + 2 + n] = (float)kmin;
      kwin = kmin;
    }
    __syncthreads();
    if (tid < 64) {                                // rewrite post outputs (exact
      const int o = tid;                           // same fmaf order as k_postm)
      const float* q = emb + (size_t)kwin * 64;
      const float* wr = ow + o * 64;
      float a = ob[o];
      for (int cch = 0; cch < 64; ++cch) a = fmaf(wr[cch], q[cch], a);
      dout[(size_t)b * 64 * DHW + (size_t)o * DHW + r] = a;
    }
    __syncthreads();                               // tdsh/dred/kwin reuse next slot
  }
}

extern "C" void kernel_launch(void* const* d_in, const int* in_sizes, int n_in,
                              void* d_out, int out_size, void* d_ws, size_t ws_size,
                              hipStream_t stream) {
  (void)in_sizes; (void)n_in; (void)out_size; (void)ws_size;
  const float* z   = (const float*)d_in[0];
  const float* emb = (const float*)d_in[1];
  const float* pw  = (const float*)d_in[2];
  const float* pb  = (const float*)d_in[3];
  const float* ow  = (const float*)d_in[4];
  const float* ob  = (const float*)d_in[5];
  float* out = (float*)d_out;
  char*  ws  = (char*)d_ws;

  hipLaunchKernelGGL(k_pre,    dim3(272), dim3(1024), 0, stream, z, emb, pw, pb, out, ws);
  hipLaunchKernelGGL(k_dist,   dim3(512), dim3(1024), 0, stream, out, ws);
  hipLaunchKernelGGL(k_postm,  dim3(256), dim3(1024), 0, stream, emb, ow, ob, out, ws);
  hipLaunchKernelGGL(k_refine, dim3(257), dim3(256),  0, stream, z, emb, pw, pb, ow, ob, out, ws);
}

// Round 17
// 171.343 us; speedup vs baseline: 1.2570x; 1.2570x over previous
//
#include <hip/hip_runtime.h>
#include <cstdint>
#include <cstddef>

typedef float  f32x4  __attribute__((ext_vector_type(4)));
typedef float  f32x16 __attribute__((ext_vector_type(16)));
typedef short  s16x8  __attribute__((ext_vector_type(8)));

#define DEV __device__ __forceinline__

static constexpr int    DHW       = 32768;       // 8*64*64
static constexpr int    NTOK      = 65536;       // B*D*H*W
static constexpr int    CHUNK_B   = 18432;       // 16384 gh/gl + 1KB e2 + zero slot + pad
static constexpr size_t OUT_ELEMS = 4194304;     // 2*64*32768
static constexpr float  BIGC      = 512.0f;      // positivity bias for uint-compare
static constexpr float  TAU       = 0.015f;      // near-tie refinement threshold
static constexpr int    FLAG_CAP  = 7424;        // sized so ws end == 2,524,416 (proven)

// workspace layout (end = 2,524,416 B)
static constexpr size_t WS_PREP = 0;             // 64*18432 = 1,179,648
static constexpr size_t WS_RESW = 1179648;       // 4*65536*4 (per-quarter winner word)
static constexpr size_t WS_RESB = 2228224;       // 4*65536*1 (chunk | tie-bit)
static constexpr size_t WS_PART = 2490368;       // 1024*4: [0..255] merge d, [256..383] t^2
static constexpr size_t WS_CNT  = 2494464;       // int
static constexpr size_t WS_FLAG = 2494720;       // FLAG_CAP*4 -> end 2,524,416

DEV unsigned f2bf(float f) {            // RNE float -> bf16 bits
  unsigned u = __float_as_uint(f);
  return (u + 0x7FFFu + ((u >> 16) & 1u)) >> 16;
}
DEV float bf2f(unsigned h) { return __uint_as_float(h << 16); }
DEV unsigned med3u(unsigned a, unsigned b, unsigned c) {
  unsigned r;
  asm("v_med3_u32 %0, %1, %2, %3" : "=v"(r) : "v"(a), "v"(b), "v"(c));
  return r;
}
DEV void gl_lds16(const void* g, void* l) {   // 64 lanes x 16B, dest = base + lane*16
  __builtin_amdgcn_global_load_lds(
      (const __attribute__((address_space(1))) unsigned int*)g,
      (__attribute__((address_space(3))) unsigned int*)l, 16, 0, 0);
}

// ---------------- Kernel A: pre-conv (t = pre_w@z + pre_b) + embedding prep ----
// t stored [C=64][NTOK] inside d_out (overwritten later by k_post).
// Conv split 4-way over output channels (grid 1024): 16 ch/thread.
__global__ __launch_bounds__(256) void k_pre(const float* __restrict__ z,
    const float* __restrict__ emb, const float* __restrict__ pw, const float* __restrict__ pb,
    float* __restrict__ dout, char* __restrict__ ws)
{
  const int blk = blockIdx.x, tid = threadIdx.x;
  if (blk == 0 && tid == 0) *(int*)(ws + WS_CNT) = 0;
  if (blk < 1024) {
    float* t = dout;
    const int v = (blk & 255) * 256 + tid;
    const int qtr = blk >> 8;                // channels qtr*16 .. qtr*16+15
    const int b = v >> 15, r = v & (DHW - 1);
    const float* zp = z + (size_t)b * 64 * DHW + r;
    float zr[64];
#pragma unroll
    for (int c2 = 0; c2 < 64; ++c2) zr[c2] = zp[(size_t)c2 * DHW];
    const int c0 = qtr * 16;
    for (int c = c0; c < c0 + 16; c += 4) {  // 4 independent chains (ILP)
      const float* w0 = pw + c * 64;
      const float* w1 = pw + (c + 1) * 64;
      const float* w2 = pw + (c + 2) * 64;
      const float* w3 = pw + (c + 3) * 64;
      float a0 = pb[c], a1 = pb[c + 1], a2 = pb[c + 2], a3 = pb[c + 3];
#pragma unroll
      for (int c2 = 0; c2 < 64; ++c2) {      // per-channel order unchanged
        const float zv = zr[c2];
        a0 = fmaf(w0[c2], zv, a0); a1 = fmaf(w1[c2], zv, a1);
        a2 = fmaf(w2[c2], zv, a2); a3 = fmaf(w3[c2], zv, a3);
      }
      t[(size_t)c * NTOK + v]       = a0;
      t[(size_t)(c + 1) * NTOK + v] = a1;
      t[(size_t)(c + 2) * NTOK + v] = a2;
      t[(size_t)(c + 3) * NTOK + v] = a3;
    }
  } else {
    const int tt = (blk - 1024) * 256 + tid; // 0..16383, 2 units each
#pragma unroll
    for (int uu = 0; uu < 2; ++uu) {
      const int u = tt * 2 + uu;
      const int k = u >> 3, j = u & 7;       // code k, 8-channel group j
      const float* ep = emb + (size_t)k * 64 + j * 8;
      unsigned hw[4], lw[4];
#pragma unroll
      for (int i = 0; i < 4; ++i) {
        float g0 = -2.0f * ep[2 * i], g1 = -2.0f * ep[2 * i + 1];
        unsigned h0 = f2bf(g0); unsigned l0 = f2bf(g0 - bf2f(h0));
        unsigned h1 = f2bf(g1); unsigned l1 = f2bf(g1 - bf2f(h1));
        hw[i] = h0 | (h1 << 16); lw[i] = l0 | (l1 << 16);
      }
      char* base = ws + WS_PREP + (size_t)(k >> 6) * CHUNK_B;
      const int r = k & 63;
      const int swz = (r & 15) << 4;
      char* rowp = base + r * 256;
      *(uint4*)(rowp + ((j * 16) ^ swz))        = make_uint4(hw[0], hw[1], hw[2], hw[3]);
      *(uint4*)(rowp + ((128 + j * 16) ^ swz))  = make_uint4(lw[0], lw[1], lw[2], lw[3]);
      if (j == 0) {
        const float* er = emb + (size_t)k * 64;
        float s = 0.f;
#pragma unroll
        for (int c = 0; c < 64; ++c) s = fmaf(er[c], er[c], s);
        s += BIGC;
        unsigned eh  = f2bf(s);
        float    rs  = s - bf2f(eh);
        unsigned el  = f2bf(rs);
        unsigned el2 = f2bf(rs - bf2f(el));
        *(uint4*)(base + 16384 + r * 16) = make_uint4(eh | (el << 16), el2, 0u, 0u);
        if (r == 0) *(uint4*)(base + 16384 + 1024) = make_uint4(0u, 0u, 0u, 0u);
      }
    }
  }
}

// ---------------- Kernel B: bf16x3 MFMA distance (32x32x16) -------------------
// r13-measured form: 512 tokens/block (16 waves), NQ=4, 2-buffer LDS.
// Prologue accumulates sum(t^2) per block -> WS_PART[256+gidx] for metric loss.
__global__ __launch_bounds__(1024, 4) void k_dist(float* __restrict__ dout,
                                                  char* __restrict__ ws)
{
  constexpr int NCH = 16;
  __shared__ __align__(16) char smem[2 * CHUNK_B];
  __shared__ float t2s[16];
  const float* t = dout;                       // [64][NTOK]
  const int tid = threadIdx.x;
  const int w = tid >> 6, lane = tid & 63;     // w in [0,16)
  const int l31 = lane & 31, khalf = lane >> 5;
  const int gidx = blockIdx.x >> 2, h = blockIdx.x & 3;
  const int tb = gidx * 512 + w * 32;
  const int tok = tb + l31;

  // ---- B-fragments: t[k][tok], k = kt*16 + khalf*8 + i; also sum t^2 ----
  s16x8 tav[4], tlv[4];
  float t2 = 0.f;
#pragma unroll
  for (int kt = 0; kt < 4; ++kt) {
    const float* tc = t + (size_t)(kt * 16 + khalf * 8) * NTOK + tok;
    float f[8];
#pragma unroll
    for (int i = 0; i < 8; ++i) f[i] = tc[(size_t)i * NTOK];
#pragma unroll
    for (int i = 0; i < 8; ++i) t2 = fmaf(f[i], f[i], t2);
    union { unsigned u[4]; s16x8 v; } xh, xl;
#pragma unroll
    for (int i = 0; i < 4; ++i) {
      unsigned h0 = f2bf(f[2 * i]),     l0 = f2bf(f[2 * i]     - bf2f(h0));
      unsigned h1 = f2bf(f[2 * i + 1]), l1 = f2bf(f[2 * i + 1] - bf2f(h1));
      xh.u[i] = h0 | (h1 << 16); xl.u[i] = l0 | (l1 << 16);
    }
    tav[kt] = xh.v; tlv[kt] = xl.v;
  }
  // token total = both khalf halves; then sum the wave's 32 tokens (fixed tree)
  t2 += __shfl_xor(t2, 32);
#pragma unroll
  for (int m = 1; m <= 16; m <<= 1) t2 += __shfl_xor(t2, m);
  if (lane == 0) t2s[w] = t2;

  s16x8 ones;                                  // B for e2-MFMA: k'=0,1,2 -> 1.0 (khalf 0)
  { union { unsigned u[4]; s16x8 v; } o;
    o.u[0] = khalf ? 0u : 0x3F803F80u;
    o.u[1] = khalf ? 0u : 0x00003F80u;
    o.u[2] = 0u; o.u[3] = 0u; ones = o.v; }

  const char* prep = ws + WS_PREP + (size_t)h * NCH * CHUNK_B;
  const int swz = (l31 & 15) << 4;

  // staging: 16 waves x 1KB covers the 16KB gh/gl; waves 0-1 add the 2KB e2 tail
  auto stage = [&](int cc) {
    const char* src = prep + (size_t)cc * CHUNK_B;
    char* dst = smem + (size_t)(cc & 1) * CHUNK_B;
    gl_lds16(src + w * 1024 + lane * 16, dst + w * 1024);
    if (w < 2) gl_lds16(src + 16384 + w * 1024 + lane * 16, dst + 16384 + w * 1024);
  };
  stage(0);
  __syncthreads();

  unsigned u1 = 0x7f800000u, u2 = 0x7f800000u;
  int c1 = 0;

  for (int c = 0; c < NCH; ++c) {
    const char* L = smem + (c & 1) * CHUNK_B;
    if (c + 1 < NCH) stage(c + 1);             // issue next-chunk stage early
    f32x16 acc0 = {}, acc1 = {};
    {                                          // e2 seed via MFMA (adds 512+||e||^2)
      const s16x8 e0 = *(const s16x8*)(L + (khalf ? (16384 + 1024) : (16384 + l31 * 16)));
      const s16x8 e1 = *(const s16x8*)(L + (khalf ? (16384 + 1024) : (16384 + (32 + l31) * 16)));
      acc0 = __builtin_amdgcn_mfma_f32_32x32x16_bf16(e0, ones, acc0, 0, 0, 0);
      acc1 = __builtin_amdgcn_mfma_f32_32x32x16_bf16(e1, ones, acc1, 0, 0, 0);
    }
#pragma unroll
    for (int kt = 0; kt < 4; ++kt) {
      const int i0 = (kt * 32 + khalf * 16) ^ swz;
      const s16x8 gh0 = *(const s16x8*)(L + l31 * 256 + i0);
      const s16x8 gl0 = *(const s16x8*)(L + l31 * 256 + (i0 ^ 128));
      const s16x8 gh1 = *(const s16x8*)(L + (32 + l31) * 256 + i0);
      const s16x8 gl1 = *(const s16x8*)(L + (32 + l31) * 256 + (i0 ^ 128));
      acc0 = __builtin_amdgcn_mfma_f32_32x32x16_bf16(gh0, tav[kt], acc0, 0, 0, 0);
      acc0 = __builtin_amdgcn_mfma_f32_32x32x16_bf16(gh0, tlv[kt], acc0, 0, 0, 0);
      acc0 = __builtin_amdgcn_mfma_f32_32x32x16_bf16(gl0, tav[kt], acc0, 0, 0, 0);
      acc1 = __builtin_amdgcn_mfma_f32_32x32x16_bf16(gh1, tav[kt], acc1, 0, 0, 0);
      acc1 = __builtin_amdgcn_mfma_f32_32x32x16_bf16(gh1, tlv[kt], acc1, 0, 0, 0);
      acc1 = __builtin_amdgcn_mfma_f32_32x32x16_bf16(gl1, tav[kt], acc1, 0, 0, 0);
    }
    // argmin: C row = (q&3)+8*(q>>2) (+32 for acc1); khalf bit |'d at end
    const unsigned p1 = u1;
#pragma unroll
    for (int q = 0; q < 16; ++q) {
      const unsigned w0 = (unsigned)((q & 3) + 8 * (q >> 2));
      unsigned v0 = (__float_as_uint(acc0[q]) & ~63u) | w0;
      u2 = med3u(u1, v0, u2); u1 = u1 < v0 ? u1 : v0;
      unsigned v1 = (__float_as_uint(acc1[q]) & ~63u) | (w0 + 32u);
      u2 = med3u(u1, v1, u2); u1 = u1 < v1 ? u1 : v1;
    }
    if (u1 != p1) c1 = c;
    __syncthreads();                           // drains vmcnt -> next chunk staged
  }

  u1 |= (unsigned)(khalf * 4);                 // complete wid (bit 2)
  // merge lane <-> lane+32 (same token, different code rows)
  const unsigned o1 = __shfl_xor(u1, 32);
  const unsigned o2 = __shfl_xor(u2, 32);
  const int      oc = __shfl_xor(c1, 32);
  const unsigned am = u1 & ~63u, om = o1 & ~63u;
  const int mycode = c1 * 64 + (int)(u1 & 63u);
  const int ocode  = oc * 64 + (int)(o1 & 63u);
  const bool owins = (om < am) || (om == am && ocode < mycode);
  const unsigned f1 = owins ? o1 : u1;
  const int      fc = owins ? oc : c1;
  const unsigned mx = owins ? am : om;
  unsigned s2 = (u2 & ~63u) < (o2 & ~63u) ? (u2 & ~63u) : (o2 & ~63u);
  s2 = s2 < mx ? s2 : mx;
  if (khalf == 0) {
    const bool nt = (__uint_as_float(s2) - __uint_as_float(f1 & ~63u)) < TAU;
    ((unsigned*)(ws + WS_RESW))[h * 65536 + tok] = f1;
    ((unsigned char*)(ws + WS_RESB))[h * 65536 + tok] =
        (unsigned char)(fc | (nt ? 0x80 : 0));   // fc in 0..15 (4 bits)
  }
  if (h == 0 && tid == 0) {                    // t^2 block partial (t2s visible:
    float s = 0.f;                             // last loop iter ended in barrier)
#pragma unroll
    for (int i = 0; i < 16; ++i) s += t2s[i];
    ((float*)(ws + WS_PART))[256 + gidx] = s;
  }
}

// ---------------- Kernel M: 4-way merge + flags + METRIC loss -----------------
// 256 blocks x 256 thr, thread-per-token. Loss via identity
// ||t-q||^2 = (metric - 512) + ||t||^2 : no t re-read, no emb gather.
__global__ __launch_bounds__(256) void k_merge(float* __restrict__ dout,
                                               char* __restrict__ ws)
{
  __shared__ float ls[4];
  const int tid = threadIdx.x;
  const int v = blockIdx.x * 256 + tid;
  const unsigned* resw = (const unsigned*)(ws + WS_RESW);
  const unsigned char* resb = (const unsigned char*)(ws + WS_RESB);
  unsigned k1 = 0xffffffffu, k2 = 0xffffffffu, bw = 0; int bq = 0;
#pragma unroll
  for (int q = 0; q < 4; ++q) {
    const unsigned W = resw[q * 65536 + v];
    const unsigned key = W & ~63u;
    if (key < k1) { k2 = k1; k1 = key; bq = q; bw = W; }
    else          { k2 = key < k2 ? key : k2; }
  }
  const unsigned char bb = resb[bq * 65536 + v];
  const int code = bq * 1024 + (int)(bb & 15u) * 64 + (int)(bw & 63u);
  dout[OUT_ELEMS + 2 + v] = (float)code;
  const bool flag = (bb & 0x80u) ||
                    (__uint_as_float(k2) - __uint_as_float(k1) < TAU);
  if (flag) {
    int p = atomicAdd((int*)(ws + WS_CNT), 1);
    if (p < FLAG_CAP) ((int*)(ws + WS_FLAG))[p] = v;
  }
  float acc = __uint_as_float(k1) - 512.0f;    // = ||e||^2 - 2e.t (+rounding)
#pragma unroll
  for (int m = 1; m <= 32; m <<= 1) acc += __shfl_xor(acc, m);  // 64-token sum
  const int lane = tid & 63, wv = tid >> 6;
  if (lane == 0) ls[wv] = acc;
  __syncthreads();
  if (tid == 0)
    ((float*)(ws + WS_PART))[blockIdx.x] = ls[0] + ls[1] + ls[2] + ls[3];
}

// ---------------- Kernel R: f64 re-scan of near-tie tokens --------------------
// Compact grid (256 blocks), each block strides slots bid, bid+256, ...
__global__ __launch_bounds__(256) void k_refine(const float* __restrict__ z,
    const float* __restrict__ emb, const float* __restrict__ pw, const float* __restrict__ pb,
    float* __restrict__ dout, char* __restrict__ ws)
{
  __shared__ double tdsh[64];
  __shared__ double dred[4]; __shared__ int kred[4];
  int cv = *(const int*)(ws + WS_CNT);
  if (cv > FLAG_CAP) cv = FLAG_CAP;
  const int tid = threadIdx.x;
  const int lane = tid & 63, wv = tid >> 6;

  for (int slot = blockIdx.x; slot < cv; slot += 256) {
    const int n = ((const int*)(ws + WS_FLAG))[slot];

    if (tid < 64) {                                // recompute token t in f64 (proven chain)
      const int b = n >> 15, r = n & (DHW - 1);
      const float* zp = z + (size_t)b * 64 * DHW + r;
      const float* wr = pw + tid * 64;
      double a = (double)pb[tid];
      for (int c2 = 0; c2 < 64; ++c2)
        a = fma((double)wr[c2], (double)zp[(size_t)c2 * DHW], a);
      tdsh[tid] = a;
    }
    __syncthreads();

    double td[64];                                 // all channels, static-indexed
#pragma unroll
    for (int j = 0; j < 64; ++j) td[j] = tdsh[j];  // broadcast reads

    double dmin = 1e300; int kmin = 0;
    for (int it = 0; it < 16; ++it) {
      const int code = it * 256 + tid;             // ascending per thread
      const float4* e = (const float4*)(emb + (size_t)code * 64);
      double d0 = 0.0, d1 = 0.0;
#pragma unroll
      for (int i = 0; i < 16; ++i) {
        const float4 ev = e[i];
        const double x0 = td[4 * i]     - (double)ev.x; d0 = fma(x0, x0, d0);
        const double x1 = td[4 * i + 1] - (double)ev.y; d1 = fma(x1, x1, d1);
        const double x2 = td[4 * i + 2] - (double)ev.z; d0 = fma(x2, x2, d0);
        const double x3 = td[4 * i + 3] - (double)ev.w; d1 = fma(x3, x3, d1);
      }
      const double d = d0 + d1;
      if (d < dmin) { dmin = d; kmin = code; }     // strict < -> lowest code kept
    }
#pragma unroll
    for (int m = 1; m < 64; m <<= 1) {             // wave argmin, lower-code tiebreak
      const double od = __shfl_xor(dmin, m);
      const int    ok = __shfl_xor(kmin, m);
      if (od < dmin || (od == dmin && ok < kmin)) { dmin = od; kmin = ok; }
    }
    if (lane == 0) { dred[wv] = dmin; kred[wv] = kmin; }
    __syncthreads();
    if (tid == 0) {
#pragma unroll
      for (int i = 1; i < 4; ++i)
        if (dred[i] < dmin || (dred[i] == dmin && kred[i] < kmin)) { dmin = dred[i]; kmin = kred[i]; }
      dout[OUT_ELEMS + 2 + n] = (float)kmin;
    }
    __syncthreads();                               // tdsh/dred reuse next slot
  }
}

// ---------------- Kernel D: post-conv (out = post_w@q + post_b) + loss final ---
// Split 4-way over output channels (grid 1024): 16 ch/thread.
__global__ __launch_bounds__(256) void k_post(const float* __restrict__ emb,
    const float* __restrict__ ow, const float* __restrict__ ob,
    float* __restrict__ dout, const char* __restrict__ ws)
{
  __shared__ float ps[256];
  const int v = (blockIdx.x & 255) * 256 + threadIdx.x;
  const int qtr = blockIdx.x >> 8;            // channels qtr*16 .. qtr*16+15
  const int b = v >> 15, r = v & (DHW - 1);
  const int code = (int)dout[OUT_ELEMS + 2 + v];
  const float* q = emb + (size_t)code * 64;
  float qr[64];
#pragma unroll
  for (int i = 0; i < 16; ++i) *(float4*)(qr + i * 4) = *(const float4*)(q + i * 4);
  float* op = dout + (size_t)b * 64 * DHW + r;
  const int o0 = qtr * 16;
  for (int o = o0; o < o0 + 16; o += 4) {     // 4 independent chains (ILP)
    const float* w0 = ow + o * 64;
    const float* w1 = ow + (o + 1) * 64;
    const float* w2 = ow + (o + 2) * 64;
    const float* w3 = ow + (o + 3) * 64;
    float a0 = ob[o], a1 = ob[o + 1], a2 = ob[o + 2], a3 = ob[o + 3];
#pragma unroll
    for (int cch = 0; cch < 64; ++cch) {      // per-channel order unchanged
      const float qv = qr[cch];
      a0 = fmaf(w0[cch], qv, a0); a1 = fmaf(w1[cch], qv, a1);
      a2 = fmaf(w2[cch], qv, a2); a3 = fmaf(w3[cch], qv, a3);
    }
    op[(size_t)o * DHW]       = a0;
    op[(size_t)(o + 1) * DHW] = a1;
    op[(size_t)(o + 2) * DHW] = a2;
    op[(size_t)(o + 3) * DHW] = a3;
  }
  if (blockIdx.x == 0) {
    // partials: [0..255] merge d-sums, [256..383] dist t^2-sums
    const float* part = (const float*)(ws + WS_PART);
    const int t4 = threadIdx.x * 4;
    float s = 0.f;
    if (threadIdx.x < 96)
      s = ((part[t4] + part[t4 + 1]) + part[t4 + 2]) + part[t4 + 3];
    ps[threadIdx.x] = s;
    __syncthreads();
    if (threadIdx.x == 0) {
      float tot = 0.f;
      for (int i = 0; i < 256; ++i) tot += ps[i];   // fixed order: deterministic
      const float mean = tot / 4194304.0f;
      dout[OUT_ELEMS]     = mean;   // codebook_loss
      dout[OUT_ELEMS + 1] = mean;   // commitment_loss
    }
  }
}

extern "C" void kernel_launch(void* const* d_in, const int* in_sizes, int n_in,
                              void* d_out, int out_size, void* d_ws, size_t ws_size,
                              hipStream_t stream) {
  (void)in_sizes; (void)n_in; (void)out_size; (void)ws_size;
  const float* z   = (const float*)d_in[0];
  const float* emb = (const float*)d_in[1];
  const float* pw  = (const float*)d_in[2];
  const float* pb  = (const float*)d_in[3];
  const float* ow  = (const float*)d_in[4];
  const float* ob  = (const float*)d_in[5];
  float* out = (float*)d_out;
  char*  ws  = (char*)d_ws;

  hipLaunchKernelGGL(k_pre,    dim3(1088), dim3(256),  0, stream, z, emb, pw, pb, out, ws);
  hipLaunchKernelGGL(k_dist,   dim3(512),  dim3(1024), 0, stream, out, ws);
  hipLaunchKernelGGL(k_merge,  dim3(256),  dim3(256),  0, stream, out, ws);
  hipLaunchKernelGGL(k_refine, dim3(256),  dim3(256),  0, stream, z, emb, pw, pb, out, ws);
  hipLaunchKernelGGL(k_post,   dim3(1024), dim3(256),  0, stream, emb, ow, ob, out, ws);
}